// Round 5
// baseline (2599.192 us; speedup 1.0000x reference)
//
#include <hip/hip_runtime.h>
#include <hip/hip_bf16.h>

#define N_NODES 50000
#define N_EDGES 1600000
#define E_TOT   1650000   // + self loops
#define IN_F    2000
#define NEG     0.2f
#define BN_EPS  1e-5f

// ws layout (float offsets). Zero-initialized region first.
#define O_AGG1  0
#define O_AGG2  3200000
#define O_DEN1  6400000
#define O_DEN2  6600000
#define O_STAT  6650000   // sum1[64] sq1[64] sum2[64] sq2[64]
#define ZERO_F  6650256
#define O_H1    6650256
#define O_H2    9850256
#define O_AS1   13050256
#define O_AD1   13250256
#define O_AS2   13450256
#define O_AD2   13500256
#define O_BN    13550256  // bnA1[64] bnB1[64] bnA2[64] bnB2[64]

__global__ __launch_bounds__(256) void k_zero(float4* __restrict__ p, int n4) {
    int i = blockIdx.x * 256 + threadIdx.x;
    int stride = gridDim.x * 256;
    float4 z = make_float4(0.f, 0.f, 0.f, 0.f);
    for (; i < n4; i += stride) p[i] = z;
}

// h1 = x @ W1 ; a_src1/a_dst1 per (node, head) in epilogue.
__global__ __launch_bounds__(256) void k_gemm1(
        const float* __restrict__ x, const float* __restrict__ W1,
        const float* __restrict__ att_s, const float* __restrict__ att_d,
        float* __restrict__ h1, float* __restrict__ as1, float* __restrict__ ad1) {
    __shared__ float lw[64][65];   // [k][c], pad 65 -> conflict-free
    const int t = threadIdx.x;
    const int lane = t & 63;
    const int wid = __builtin_amdgcn_readfirstlane(t >> 6);
    const int rowBase = blockIdx.x * 32 + wid * 8;

    float acc[8];
#pragma unroll
    for (int r = 0; r < 8; ++r) acc[r] = 0.f;

    const float* xrow[8];
#pragma unroll
    for (int r = 0; r < 8; ++r) {
        int row = rowBase + r;
        if (row >= N_NODES) row = N_NODES - 1;   // clamp loads; stores guarded
        xrow[r] = x + (size_t)row * IN_F;
    }

    for (int kb = 0; kb < IN_F; kb += 64) {
        const int klen = min(64, IN_F - kb);
        __syncthreads();
        const float4* wsrc = (const float4*)(W1 + kb * 64);
        for (int v = t; v < klen * 16; v += 256) {
            float4 w4 = wsrc[v];
            int k = v >> 4, c = (v & 15) << 2;
            lw[k][c] = w4.x; lw[k][c + 1] = w4.y; lw[k][c + 2] = w4.z; lw[k][c + 3] = w4.w;
        }
        __syncthreads();
        for (int k0 = 0; k0 < klen; k0 += 4) {
            float w0 = lw[k0][lane], w1 = lw[k0 + 1][lane];
            float w2 = lw[k0 + 2][lane], w3 = lw[k0 + 3][lane];
#pragma unroll
            for (int r = 0; r < 8; ++r) {
                float4 xv = *(const float4*)(xrow[r] + kb + k0);
                acc[r] = fmaf(xv.x, w0, acc[r]);
                acc[r] = fmaf(xv.y, w1, acc[r]);
                acc[r] = fmaf(xv.z, w2, acc[r]);
                acc[r] = fmaf(xv.w, w3, acc[r]);
            }
        }
    }

    const float asv = att_s[lane], adv = att_d[lane];
#pragma unroll
    for (int r = 0; r < 8; ++r) {
        int row = rowBase + r;
        if (row >= N_NODES) continue;            // wave-uniform -> no divergence
        h1[(size_t)row * 64 + lane] = acc[r];
        float vs = acc[r] * asv;
        float vd = acc[r] * adv;
#pragma unroll
        for (int off = 8; off >= 1; off >>= 1) { // reduce within 16-lane head group
            vs += __shfl_xor(vs, off, 64);
            vd += __shfl_xor(vd, off, 64);
        }
        if ((lane & 15) == 0) {
            as1[row * 4 + (lane >> 4)] = vs;
            ad1[row * 4 + (lane >> 4)] = vd;
        }
    }
}

// denom1[d,h] += exp(lrelu(a_src[s,h]+a_dst[d,h]))  (no max-shift; |e| small)
__global__ __launch_bounds__(256) void k_den1(
        const int* __restrict__ ei, const float* __restrict__ as1,
        const float* __restrict__ ad1, float* __restrict__ den) {
    int e = blockIdx.x * 256 + threadIdx.x;
    if (e >= E_TOT) return;
    int s, d;
    if (e < N_EDGES) { s = ei[e]; d = ei[N_EDGES + e]; } else { s = d = e - N_EDGES; }
    float4 a = *(const float4*)(as1 + s * 4);
    float4 b = *(const float4*)(ad1 + d * 4);
    float v;
    v = a.x + b.x; v = v > 0.f ? v : NEG * v; atomicAdd(&den[d * 4 + 0], __expf(v));
    v = a.y + b.y; v = v > 0.f ? v : NEG * v; atomicAdd(&den[d * 4 + 1], __expf(v));
    v = a.z + b.z; v = v > 0.f ? v : NEG * v; atomicAdd(&den[d * 4 + 2], __expf(v));
    v = a.w + b.w; v = v > 0.f ? v : NEG * v; atomicAdd(&den[d * 4 + 3], __expf(v));
}

// wave per edge, lane = channel: agg1[d,c] += alpha(h) * h1[s,c]
__global__ __launch_bounds__(256) void k_agg1k(
        const int* __restrict__ ei, const float* __restrict__ as1,
        const float* __restrict__ ad1, const float* __restrict__ den,
        const float* __restrict__ h1, float* __restrict__ agg) {
    int gid = blockIdx.x * 256 + threadIdx.x;
    int e = gid >> 6;
    if (e >= E_TOT) return;
    int lane = gid & 63;
    int s, d;
    if (e < N_EDGES) { s = ei[e]; d = ei[N_EDGES + e]; } else { s = d = e - N_EDGES; }
    int h = lane >> 4;
    float a = as1[s * 4 + h] + ad1[d * 4 + h];
    a = a > 0.f ? a : NEG * a;
    float alpha = __expf(a) / (den[d * 4 + h] + 1e-16f);
    atomicAdd(&agg[(size_t)d * 64 + lane], alpha * h1[(size_t)s * 64 + lane]);
}

// per-feature sum / sumsq over nodes
__global__ __launch_bounds__(256) void k_stats(
        const float* __restrict__ v, float* __restrict__ sum, float* __restrict__ sq) {
    __shared__ float ls[4][64], lq[4][64];
    int t = threadIdx.x, f = t & 63, sub = t >> 6;
    float s = 0.f, q = 0.f;
    for (int row = blockIdx.x * 4 + sub; row < N_NODES; row += gridDim.x * 4) {
        float val = v[(size_t)row * 64 + f];
        s += val; q = fmaf(val, val, q);
    }
    ls[sub][f] = s; lq[sub][f] = q;
    __syncthreads();
    if (t < 64) {
        s = ls[0][t] + ls[1][t] + ls[2][t] + ls[3][t];
        q = lq[0][t] + lq[1][t] + lq[2][t] + lq[3][t];
        atomicAdd(&sum[t], s);
        atomicAdd(&sq[t], q);
    }
}

// bnA = gamma*rsqrt(var+eps); bnB = beta - mean*bnA   (pre-BN bias cancels)
__global__ void k_bnfin(const float* __restrict__ sum, const float* __restrict__ sq,
                        const float* __restrict__ gamma, const float* __restrict__ beta,
                        float* __restrict__ bnA, float* __restrict__ bnB) {
    int f = threadIdx.x;
    if (f < 64) {
        float mean = sum[f] * (1.f / N_NODES);
        float var = sq[f] * (1.f / N_NODES) - mean * mean;
        float sc = gamma[f] * rsqrtf(var + BN_EPS);
        bnA[f] = sc;
        bnB[f] = fmaf(-mean, sc, beta[f]);
    }
}

// h2 = BN1(agg1) @ W2 ; a_src2/a_dst2 in epilogue (single head, 64 ch)
__global__ __launch_bounds__(256) void k_gemm2(
        const float* __restrict__ agg1, const float* __restrict__ W2,
        const float* __restrict__ bnA, const float* __restrict__ bnB,
        const float* __restrict__ att_s, const float* __restrict__ att_d,
        float* __restrict__ h2, float* __restrict__ as2, float* __restrict__ ad2) {
    __shared__ float lw[64][65];
    const int t = threadIdx.x;
    const int lane = t & 63;
    const int wid = __builtin_amdgcn_readfirstlane(t >> 6);
    const int rowBase = blockIdx.x * 32 + wid * 8;

    {
        const float4* wsrc = (const float4*)W2;
        for (int v = t; v < 1024; v += 256) {
            float4 w4 = wsrc[v];
            int k = v >> 4, c = (v & 15) << 2;
            lw[k][c] = w4.x; lw[k][c + 1] = w4.y; lw[k][c + 2] = w4.z; lw[k][c + 3] = w4.w;
        }
    }
    __syncthreads();

    float acc[8];
#pragma unroll
    for (int r = 0; r < 8; ++r) acc[r] = 0.f;
    const float* arow[8];
#pragma unroll
    for (int r = 0; r < 8; ++r) {
        int row = rowBase + r;
        if (row >= N_NODES) row = N_NODES - 1;
        arow[r] = agg1 + (size_t)row * 64;
    }

    for (int k0 = 0; k0 < 64; k0 += 4) {
        float w0 = lw[k0][lane], w1 = lw[k0 + 1][lane];
        float w2 = lw[k0 + 2][lane], w3 = lw[k0 + 3][lane];
        float4 A = *(const float4*)(bnA + k0);
        float4 B = *(const float4*)(bnB + k0);
#pragma unroll
        for (int r = 0; r < 8; ++r) {
            float4 av = *(const float4*)(arow[r] + k0);
            float h0 = fmaf(av.x, A.x, B.x);
            float h1v = fmaf(av.y, A.y, B.y);
            float h2v = fmaf(av.z, A.z, B.z);
            float h3 = fmaf(av.w, A.w, B.w);
            acc[r] = fmaf(h0, w0, acc[r]);
            acc[r] = fmaf(h1v, w1, acc[r]);
            acc[r] = fmaf(h2v, w2, acc[r]);
            acc[r] = fmaf(h3, w3, acc[r]);
        }
    }

    const float asv = att_s[lane], adv = att_d[lane];
#pragma unroll
    for (int r = 0; r < 8; ++r) {
        int row = rowBase + r;
        if (row >= N_NODES) continue;
        h2[(size_t)row * 64 + lane] = acc[r];
        float vs = acc[r] * asv;
        float vd = acc[r] * adv;
#pragma unroll
        for (int off = 32; off >= 1; off >>= 1) {
            vs += __shfl_xor(vs, off, 64);
            vd += __shfl_xor(vd, off, 64);
        }
        if (lane == 0) { as2[row] = vs; ad2[row] = vd; }
    }
}

__global__ __launch_bounds__(256) void k_den2(
        const int* __restrict__ ei, const float* __restrict__ as2,
        const float* __restrict__ ad2, float* __restrict__ den) {
    int e = blockIdx.x * 256 + threadIdx.x;
    if (e >= E_TOT) return;
    int s, d;
    if (e < N_EDGES) { s = ei[e]; d = ei[N_EDGES + e]; } else { s = d = e - N_EDGES; }
    float v = as2[s] + ad2[d];
    v = v > 0.f ? v : NEG * v;
    atomicAdd(&den[d], __expf(v));
}

__global__ __launch_bounds__(256) void k_agg2k(
        const int* __restrict__ ei, const float* __restrict__ as2,
        const float* __restrict__ ad2, const float* __restrict__ den,
        const float* __restrict__ h2, float* __restrict__ agg) {
    int gid = blockIdx.x * 256 + threadIdx.x;
    int e = gid >> 6;
    if (e >= E_TOT) return;
    int lane = gid & 63;
    int s, d;
    if (e < N_EDGES) { s = ei[e]; d = ei[N_EDGES + e]; } else { s = d = e - N_EDGES; }
    float a = as2[s] + ad2[d];
    a = a > 0.f ? a : NEG * a;
    float alpha = __expf(a) / (den[d] + 1e-16f);
    atomicAdd(&agg[(size_t)d * 64 + lane], alpha * h2[(size_t)s * 64 + lane]);
}

__global__ __launch_bounds__(256) void k_apply(
        const float* __restrict__ agg, const float* __restrict__ bnA,
        const float* __restrict__ bnB, float* __restrict__ out) {
    int i = blockIdx.x * 256 + threadIdx.x;   // float4 index
    if (i >= N_NODES * 16) return;
    int f4 = i & 15;
    float4 v = ((const float4*)agg)[i];
    float4 A = ((const float4*)bnA)[f4];
    float4 B = ((const float4*)bnB)[f4];
    float4 o;
    o.x = fmaf(v.x, A.x, B.x);
    o.y = fmaf(v.y, A.y, B.y);
    o.z = fmaf(v.z, A.z, B.z);
    o.w = fmaf(v.w, A.w, B.w);
    ((float4*)out)[i] = o;
}

extern "C" void kernel_launch(void* const* d_in, const int* in_sizes, int n_in,
                              void* d_out, int out_size, void* d_ws, size_t ws_size,
                              hipStream_t stream) {
    const float* x        = (const float*)d_in[0];
    const int*   ei       = (const int*)d_in[1];
    const float* W1       = (const float*)d_in[2];
    const float* att_src1 = (const float*)d_in[3];
    const float* att_dst1 = (const float*)d_in[4];
    const float* gamma1   = (const float*)d_in[6];
    const float* beta1    = (const float*)d_in[7];
    const float* W2       = (const float*)d_in[8];
    const float* att_src2 = (const float*)d_in[9];
    const float* att_dst2 = (const float*)d_in[10];
    const float* gamma2   = (const float*)d_in[12];
    const float* beta2    = (const float*)d_in[13];
    float* out = (float*)d_out;
    float* W   = (float*)d_ws;

    float* agg1 = W + O_AGG1;  float* agg2 = W + O_AGG2;
    float* den1 = W + O_DEN1;  float* den2 = W + O_DEN2;
    float* stat = W + O_STAT;
    float* h1   = W + O_H1;    float* h2   = W + O_H2;
    float* as1  = W + O_AS1;   float* ad1  = W + O_AD1;
    float* as2  = W + O_AS2;   float* ad2  = W + O_AD2;
    float* bn   = W + O_BN;

    // 1. zero accumulators (ws is poisoned 0xAA before every launch)
    k_zero<<<2048, 256, 0, stream>>>((float4*)W, ZERO_F / 4);

    // 2. layer-1 linear + attention coefficients
    k_gemm1<<<(N_NODES + 31) / 32, 256, 0, stream>>>(x, W1, att_src1, att_dst1, h1, as1, ad1);

    // 3. softmax denominators, 4 heads
    k_den1<<<(E_TOT + 255) / 256, 256, 0, stream>>>(ei, as1, ad1, den1);

    // 4. attention-weighted aggregation (wave per edge)
    k_agg1k<<<(E_TOT * 64 + 255) / 256, 256, 0, stream>>>(ei, as1, ad1, den1, h1, agg1);

    // 5-6. BN1 stats + coefficients (bias b1 cancels in BN)
    k_stats<<<256, 256, 0, stream>>>(agg1, stat + 0, stat + 64);
    k_bnfin<<<1, 64, 0, stream>>>(stat + 0, stat + 64, gamma1, beta1, bn + 0, bn + 64);

    // 7. layer-2 linear with fused BN1 affine; attention coefficients
    k_gemm2<<<(N_NODES + 31) / 32, 256, 0, stream>>>(agg1, W2, bn + 0, bn + 64,
                                                     att_src2, att_dst2, h2, as2, ad2);

    // 8-9. layer-2 softmax denominators + aggregation
    k_den2<<<(E_TOT + 255) / 256, 256, 0, stream>>>(ei, as2, ad2, den2);
    k_agg2k<<<(E_TOT * 64 + 255) / 256, 256, 0, stream>>>(ei, as2, ad2, den2, h2, agg2);

    // 10-12. BN2 + write output (b2 cancels in BN)
    k_stats<<<256, 256, 0, stream>>>(agg2, stat + 128, stat + 192);
    k_bnfin<<<1, 64, 0, stream>>>(stat + 128, stat + 192, gamma2, beta2, bn + 128, bn + 192);
    k_apply<<<(N_NODES * 16 + 255) / 256, 256, 0, stream>>>(agg2, bn + 128, bn + 192, out);
}

// Round 6
// 1877.798 us; speedup vs baseline: 1.3842x; 1.3842x over previous
//
#include <hip/hip_runtime.h>
#include <hip/hip_bf16.h>

#define N_NODES 50000
#define N_EDGES 1600000
#define E_TOT   1650000   // + self loops
#define IN_F    2000
#define NEG     0.2f
#define BN_EPS  1e-5f

// ws layout (float offsets). Zero-initialized region first.
#define O_AGG1  0
#define O_AGG2  3200000
#define O_DEN1  6400000
#define O_DEN2  6600000
#define O_STAT  6650000   // sum1[64] sq1[64] sum2[64] sq2[64]
#define ZERO_F  6650256
#define O_H1    6650256
#define O_H2    9850256
#define O_AS1   13050256
#define O_AD1   13250256
#define O_AS2   13450256
#define O_AD2   13500256
#define O_BN    13550256  // bnA1[64] bnB1[64] bnA2[64] bnB2[64]

__global__ __launch_bounds__(256) void k_zero(float4* __restrict__ p, int n4) {
    int i = blockIdx.x * 256 + threadIdx.x;
    int stride = gridDim.x * 256;
    float4 z = make_float4(0.f, 0.f, 0.f, 0.f);
    for (; i < n4; i += stride) p[i] = z;
}

// h1 = x @ W1. Tiled fp32 GEMM: 64 rows x 64 cols per block, K-tile 16.
// Both tiles in LDS; x tile stored transposed [k][row]; b128 fragment reads;
// register-prefetch of next K-tile hides HBM latency under the FMA loop.
__global__ __launch_bounds__(256) void k_gemm1(
        const float* __restrict__ x, const float* __restrict__ W1,
        float* __restrict__ h1) {
    __shared__ float lx[16][68];   // [k][row], pad 68: staging writes <=2-way
    __shared__ float lw[16][68];   // [k][col], pad 68: staging writes conflict-free
    const int t  = threadIdx.x;
    const int tx = t & 15;         // col group (4 cols)
    const int ty = t >> 4;         // row group (4 rows)
    const int row0 = blockIdx.x * 64;

    // staging assignments
    const int xr = t >> 2;               // x: row within tile (0..63)
    const int xk = (t & 3) << 2;         // x: k offset (0,4,8,12)
    const int wk = t >> 4;               // W: k row (0..15)
    const int wc = (t & 15) << 2;        // W: col offset (0..60)

    int xrow = row0 + xr;
    if (xrow >= N_NODES) xrow = N_NODES - 1;     // clamp loads; stores guarded
    const float* xp = x + (size_t)xrow * IN_F + xk;
    const float* wp = W1 + wk * 64 + wc;

    float4 xreg = *(const float4*)xp;            // prefetch K-tile 0
    float4 wreg = *(const float4*)wp;

    float acc[4][4];
#pragma unroll
    for (int i = 0; i < 4; ++i)
#pragma unroll
        for (int j = 0; j < 4; ++j) acc[i][j] = 0.f;

    for (int kt = 0; kt < 125; ++kt) {
        // commit staged registers to LDS (transpose x)
        lx[xk + 0][xr] = xreg.x;
        lx[xk + 1][xr] = xreg.y;
        lx[xk + 2][xr] = xreg.z;
        lx[xk + 3][xr] = xreg.w;
        *(float4*)&lw[wk][wc] = wreg;
        __syncthreads();
        // issue next tile's global loads (latency hidden by inner loop)
        if (kt + 1 < 125) {
            xreg = *(const float4*)(xp + (kt + 1) * 16);
            wreg = *(const float4*)(wp + (size_t)(kt + 1) * 16 * 64);
        }
#pragma unroll
        for (int k = 0; k < 16; ++k) {
            float4 a = *(const float4*)&lx[k][ty << 2];
            float4 b = *(const float4*)&lw[k][tx << 2];
            acc[0][0] = fmaf(a.x, b.x, acc[0][0]);
            acc[0][1] = fmaf(a.x, b.y, acc[0][1]);
            acc[0][2] = fmaf(a.x, b.z, acc[0][2]);
            acc[0][3] = fmaf(a.x, b.w, acc[0][3]);
            acc[1][0] = fmaf(a.y, b.x, acc[1][0]);
            acc[1][1] = fmaf(a.y, b.y, acc[1][1]);
            acc[1][2] = fmaf(a.y, b.z, acc[1][2]);
            acc[1][3] = fmaf(a.y, b.w, acc[1][3]);
            acc[2][0] = fmaf(a.z, b.x, acc[2][0]);
            acc[2][1] = fmaf(a.z, b.y, acc[2][1]);
            acc[2][2] = fmaf(a.z, b.z, acc[2][2]);
            acc[2][3] = fmaf(a.z, b.w, acc[2][3]);
            acc[3][0] = fmaf(a.w, b.x, acc[3][0]);
            acc[3][1] = fmaf(a.w, b.y, acc[3][1]);
            acc[3][2] = fmaf(a.w, b.z, acc[3][2]);
            acc[3][3] = fmaf(a.w, b.w, acc[3][3]);
        }
        __syncthreads();
    }

#pragma unroll
    for (int i = 0; i < 4; ++i) {
        int row = row0 + (ty << 2) + i;
        if (row < N_NODES) {
            float4 o = make_float4(acc[i][0], acc[i][1], acc[i][2], acc[i][3]);
            *(float4*)&h1[(size_t)row * 64 + (tx << 2)] = o;
        }
    }
}

// as1/ad1: per (node, head) dot of h1 row-segment with att vectors.
__global__ __launch_bounds__(256) void k_att1(
        const float* __restrict__ h1, const float* __restrict__ att_s,
        const float* __restrict__ att_d, float* __restrict__ as1,
        float* __restrict__ ad1) {
    int t = blockIdx.x * 256 + threadIdx.x;
    int node = t >> 2, h = t & 3;
    if (node >= N_NODES) return;
    const float4* hp = (const float4*)(h1 + (size_t)node * 64 + h * 16);
    const float4* sp = (const float4*)(att_s + h * 16);
    const float4* dp = (const float4*)(att_d + h * 16);
    float vs = 0.f, vd = 0.f;
#pragma unroll
    for (int j = 0; j < 4; ++j) {
        float4 hv = hp[j], s = sp[j], d = dp[j];
        vs += hv.x * s.x + hv.y * s.y + hv.z * s.z + hv.w * s.w;
        vd += hv.x * d.x + hv.y * d.y + hv.z * d.z + hv.w * d.w;
    }
    as1[node * 4 + h] = vs;
    ad1[node * 4 + h] = vd;
}

// denom1[d,h] += exp(lrelu(a_src[s,h]+a_dst[d,h]))  (no max-shift; |e| small)
__global__ __launch_bounds__(256) void k_den1(
        const int* __restrict__ ei, const float* __restrict__ as1,
        const float* __restrict__ ad1, float* __restrict__ den) {
    int e = blockIdx.x * 256 + threadIdx.x;
    if (e >= E_TOT) return;
    int s, d;
    if (e < N_EDGES) { s = ei[e]; d = ei[N_EDGES + e]; } else { s = d = e - N_EDGES; }
    float4 a = *(const float4*)(as1 + s * 4);
    float4 b = *(const float4*)(ad1 + d * 4);
    float v;
    v = a.x + b.x; v = v > 0.f ? v : NEG * v; atomicAdd(&den[d * 4 + 0], __expf(v));
    v = a.y + b.y; v = v > 0.f ? v : NEG * v; atomicAdd(&den[d * 4 + 1], __expf(v));
    v = a.z + b.z; v = v > 0.f ? v : NEG * v; atomicAdd(&den[d * 4 + 2], __expf(v));
    v = a.w + b.w; v = v > 0.f ? v : NEG * v; atomicAdd(&den[d * 4 + 3], __expf(v));
}

// wave per edge, lane = channel: agg1[d,c] += alpha(h) * h1[s,c]
__global__ __launch_bounds__(256) void k_agg1k(
        const int* __restrict__ ei, const float* __restrict__ as1,
        const float* __restrict__ ad1, const float* __restrict__ den,
        const float* __restrict__ h1, float* __restrict__ agg) {
    int gid = blockIdx.x * 256 + threadIdx.x;
    int e = gid >> 6;
    if (e >= E_TOT) return;
    int lane = gid & 63;
    int s, d;
    if (e < N_EDGES) { s = ei[e]; d = ei[N_EDGES + e]; } else { s = d = e - N_EDGES; }
    int h = lane >> 4;
    float a = as1[s * 4 + h] + ad1[d * 4 + h];
    a = a > 0.f ? a : NEG * a;
    float alpha = __expf(a) / (den[d * 4 + h] + 1e-16f);
    atomicAdd(&agg[(size_t)d * 64 + lane], alpha * h1[(size_t)s * 64 + lane]);
}

// per-feature sum / sumsq over nodes
__global__ __launch_bounds__(256) void k_stats(
        const float* __restrict__ v, float* __restrict__ sum, float* __restrict__ sq) {
    __shared__ float ls[4][64], lq[4][64];
    int t = threadIdx.x, f = t & 63, sub = t >> 6;
    float s = 0.f, q = 0.f;
    for (int row = blockIdx.x * 4 + sub; row < N_NODES; row += gridDim.x * 4) {
        float val = v[(size_t)row * 64 + f];
        s += val; q = fmaf(val, val, q);
    }
    ls[sub][f] = s; lq[sub][f] = q;
    __syncthreads();
    if (t < 64) {
        s = ls[0][t] + ls[1][t] + ls[2][t] + ls[3][t];
        q = lq[0][t] + lq[1][t] + lq[2][t] + lq[3][t];
        atomicAdd(&sum[t], s);
        atomicAdd(&sq[t], q);
    }
}

// bnA = gamma*rsqrt(var+eps); bnB = beta - mean*bnA   (pre-BN bias cancels)
__global__ void k_bnfin(const float* __restrict__ sum, const float* __restrict__ sq,
                        const float* __restrict__ gamma, const float* __restrict__ beta,
                        float* __restrict__ bnA, float* __restrict__ bnB) {
    int f = threadIdx.x;
    if (f < 64) {
        float mean = sum[f] * (1.f / N_NODES);
        float var = sq[f] * (1.f / N_NODES) - mean * mean;
        float sc = gamma[f] * rsqrtf(var + BN_EPS);
        bnA[f] = sc;
        bnB[f] = fmaf(-mean, sc, beta[f]);
    }
}

// h2 = BN1(agg1) @ W2 ; a_src2/a_dst2 in epilogue (single head, 64 ch)
__global__ __launch_bounds__(256) void k_gemm2(
        const float* __restrict__ agg1, const float* __restrict__ W2,
        const float* __restrict__ bnA, const float* __restrict__ bnB,
        const float* __restrict__ att_s, const float* __restrict__ att_d,
        float* __restrict__ h2, float* __restrict__ as2, float* __restrict__ ad2) {
    __shared__ float lw[64][65];
    const int t = threadIdx.x;
    const int lane = t & 63;
    const int wid = __builtin_amdgcn_readfirstlane(t >> 6);
    const int rowBase = blockIdx.x * 32 + wid * 8;

    {
        const float4* wsrc = (const float4*)W2;
        for (int v = t; v < 1024; v += 256) {
            float4 w4 = wsrc[v];
            int k = v >> 4, c = (v & 15) << 2;
            lw[k][c] = w4.x; lw[k][c + 1] = w4.y; lw[k][c + 2] = w4.z; lw[k][c + 3] = w4.w;
        }
    }
    __syncthreads();

    float acc[8];
#pragma unroll
    for (int r = 0; r < 8; ++r) acc[r] = 0.f;
    const float* arow[8];
#pragma unroll
    for (int r = 0; r < 8; ++r) {
        int row = rowBase + r;
        if (row >= N_NODES) row = N_NODES - 1;
        arow[r] = agg1 + (size_t)row * 64;
    }

    for (int k0 = 0; k0 < 64; k0 += 4) {
        float w0 = lw[k0][lane], w1 = lw[k0 + 1][lane];
        float w2 = lw[k0 + 2][lane], w3 = lw[k0 + 3][lane];
        float4 A = *(const float4*)(bnA + k0);
        float4 B = *(const float4*)(bnB + k0);
#pragma unroll
        for (int r = 0; r < 8; ++r) {
            float4 av = *(const float4*)(arow[r] + k0);
            float h0 = fmaf(av.x, A.x, B.x);
            float h1v = fmaf(av.y, A.y, B.y);
            float h2v = fmaf(av.z, A.z, B.z);
            float h3 = fmaf(av.w, A.w, B.w);
            acc[r] = fmaf(h0, w0, acc[r]);
            acc[r] = fmaf(h1v, w1, acc[r]);
            acc[r] = fmaf(h2v, w2, acc[r]);
            acc[r] = fmaf(h3, w3, acc[r]);
        }
    }

    const float asv = att_s[lane], adv = att_d[lane];
#pragma unroll
    for (int r = 0; r < 8; ++r) {
        int row = rowBase + r;
        if (row >= N_NODES) continue;
        h2[(size_t)row * 64 + lane] = acc[r];
        float vs = acc[r] * asv;
        float vd = acc[r] * adv;
#pragma unroll
        for (int off = 32; off >= 1; off >>= 1) {
            vs += __shfl_xor(vs, off, 64);
            vd += __shfl_xor(vd, off, 64);
        }
        if (lane == 0) { as2[row] = vs; ad2[row] = vd; }
    }
}

__global__ __launch_bounds__(256) void k_den2(
        const int* __restrict__ ei, const float* __restrict__ as2,
        const float* __restrict__ ad2, float* __restrict__ den) {
    int e = blockIdx.x * 256 + threadIdx.x;
    if (e >= E_TOT) return;
    int s, d;
    if (e < N_EDGES) { s = ei[e]; d = ei[N_EDGES + e]; } else { s = d = e - N_EDGES; }
    float v = as2[s] + ad2[d];
    v = v > 0.f ? v : NEG * v;
    atomicAdd(&den[d], __expf(v));
}

__global__ __launch_bounds__(256) void k_agg2k(
        const int* __restrict__ ei, const float* __restrict__ as2,
        const float* __restrict__ ad2, const float* __restrict__ den,
        const float* __restrict__ h2, float* __restrict__ agg) {
    int gid = blockIdx.x * 256 + threadIdx.x;
    int e = gid >> 6;
    if (e >= E_TOT) return;
    int lane = gid & 63;
    int s, d;
    if (e < N_EDGES) { s = ei[e]; d = ei[N_EDGES + e]; } else { s = d = e - N_EDGES; }
    float a = as2[s] + ad2[d];
    a = a > 0.f ? a : NEG * a;
    float alpha = __expf(a) / (den[d] + 1e-16f);
    atomicAdd(&agg[(size_t)d * 64 + lane], alpha * h2[(size_t)s * 64 + lane]);
}

__global__ __launch_bounds__(256) void k_apply(
        const float* __restrict__ agg, const float* __restrict__ bnA,
        const float* __restrict__ bnB, float* __restrict__ out) {
    int i = blockIdx.x * 256 + threadIdx.x;   // float4 index
    if (i >= N_NODES * 16) return;
    int f4 = i & 15;
    float4 v = ((const float4*)agg)[i];
    float4 A = ((const float4*)bnA)[f4];
    float4 B = ((const float4*)bnB)[f4];
    float4 o;
    o.x = fmaf(v.x, A.x, B.x);
    o.y = fmaf(v.y, A.y, B.y);
    o.z = fmaf(v.z, A.z, B.z);
    o.w = fmaf(v.w, A.w, B.w);
    ((float4*)out)[i] = o;
}

extern "C" void kernel_launch(void* const* d_in, const int* in_sizes, int n_in,
                              void* d_out, int out_size, void* d_ws, size_t ws_size,
                              hipStream_t stream) {
    const float* x        = (const float*)d_in[0];
    const int*   ei       = (const int*)d_in[1];
    const float* W1       = (const float*)d_in[2];
    const float* att_src1 = (const float*)d_in[3];
    const float* att_dst1 = (const float*)d_in[4];
    const float* gamma1   = (const float*)d_in[6];
    const float* beta1    = (const float*)d_in[7];
    const float* W2       = (const float*)d_in[8];
    const float* att_src2 = (const float*)d_in[9];
    const float* att_dst2 = (const float*)d_in[10];
    const float* gamma2   = (const float*)d_in[12];
    const float* beta2    = (const float*)d_in[13];
    float* out = (float*)d_out;
    float* W   = (float*)d_ws;

    float* agg1 = W + O_AGG1;  float* agg2 = W + O_AGG2;
    float* den1 = W + O_DEN1;  float* den2 = W + O_DEN2;
    float* stat = W + O_STAT;
    float* h1   = W + O_H1;    float* h2   = W + O_H2;
    float* as1  = W + O_AS1;   float* ad1  = W + O_AD1;
    float* as2  = W + O_AS2;   float* ad2  = W + O_AD2;
    float* bn   = W + O_BN;

    // 1. zero accumulators (ws is poisoned 0xAA before every launch)
    k_zero<<<2048, 256, 0, stream>>>((float4*)W, ZERO_F / 4);

    // 2. layer-1 linear (tiled LDS GEMM) + attention coefficients
    k_gemm1<<<(N_NODES + 63) / 64, 256, 0, stream>>>(x, W1, h1);
    k_att1<<<(N_NODES * 4 + 255) / 256, 256, 0, stream>>>(h1, att_src1, att_dst1, as1, ad1);

    // 3. softmax denominators, 4 heads
    k_den1<<<(E_TOT + 255) / 256, 256, 0, stream>>>(ei, as1, ad1, den1);

    // 4. attention-weighted aggregation (wave per edge)
    k_agg1k<<<(E_TOT * 64 + 255) / 256, 256, 0, stream>>>(ei, as1, ad1, den1, h1, agg1);

    // 5-6. BN1 stats + coefficients (bias b1 cancels in BN)
    k_stats<<<256, 256, 0, stream>>>(agg1, stat + 0, stat + 64);
    k_bnfin<<<1, 64, 0, stream>>>(stat + 0, stat + 64, gamma1, beta1, bn + 0, bn + 64);

    // 7. layer-2 linear with fused BN1 affine; attention coefficients
    k_gemm2<<<(N_NODES + 31) / 32, 256, 0, stream>>>(agg1, W2, bn + 0, bn + 64,
                                                     att_src2, att_dst2, h2, as2, ad2);

    // 8-9. layer-2 softmax denominators + aggregation
    k_den2<<<(E_TOT + 255) / 256, 256, 0, stream>>>(ei, as2, ad2, den2);
    k_agg2k<<<(E_TOT * 64 + 255) / 256, 256, 0, stream>>>(ei, as2, ad2, den2, h2, agg2);

    // 10-12. BN2 + write output (b2 cancels in BN)
    k_stats<<<256, 256, 0, stream>>>(agg2, stat + 128, stat + 192);
    k_bnfin<<<1, 64, 0, stream>>>(stat + 128, stat + 192, gamma2, beta2, bn + 128, bn + 192);
    k_apply<<<(N_NODES * 16 + 255) / 256, 256, 0, stream>>>(agg2, bn + 128, bn + 192, out);
}